// Round 1
// baseline (659.857 us; speedup 1.0000x reference)
//
#include <hip/hip_runtime.h>

#define C_IN  32
#define C_OUT 64
#define KK    27

// ---------------------------------------------------------------------------
// Kernel 1: out[n, c] = bias[c] for all n (vectorized float4 stores)
// ---------------------------------------------------------------------------
__global__ __launch_bounds__(256) void sic_init_bias(float4* __restrict__ out4,
                                                     const float4* __restrict__ bias4,
                                                     int total4) {
    int idx    = blockIdx.x * 256 + threadIdx.x;
    int stride = gridDim.x * 256;
    for (int i = idx; i < total4; i += stride) {
        out4[i] = bias4[i & 15];   // 64 channels = 16 float4 groups
    }
}

// ---------------------------------------------------------------------------
// Kernel 2: rulebook gather -> 32x64 matvec -> atomic scatter-add
// One wave (64 lanes) per (k, p) pair; lane = output channel.
// blockIdx.y = k  (weight[k] column held in 32 VGPRs per lane)
// ---------------------------------------------------------------------------
__global__ __launch_bounds__(256) void sic_scatter(
    const float* __restrict__ feats,    // [N_in, 32]
    const float* __restrict__ weight,   // [27, 32, 64]
    const int*   __restrict__ bwd,      // [N_in]
    const int*   __restrict__ in_idx,   // [27, P]
    const int*   __restrict__ out_idx,  // [27, P]
    float*       __restrict__ out,      // [N_out, 64]
    int n_in)
{
    const int k    = blockIdx.y;
    const int lane = threadIdx.x & 63;
    const int wid  = threadIdx.x >> 6;

    // Per-lane weight column W[k][0..31][lane] -> 32 VGPRs.
    // Each of the 32 loads is a fully-coalesced 256B wave read (L2-hot).
    float w[C_IN];
    const float* wk = weight + k * (C_IN * C_OUT);
#pragma unroll
    for (int i = 0; i < C_IN; ++i) w[i] = wk[i * C_OUT + lane];

    const int waves_total = gridDim.x * 4;          // waves cooperating on this k
    const long long base  = (long long)k * n_in;

    for (int p = blockIdx.x * 4 + wid; p < n_in; p += waves_total) {
        // Wave-uniform rulebook entry (all lanes same address -> 1 transaction)
        int src = in_idx[base + p];
        int dst = out_idx[base + p];
        src = __builtin_amdgcn_readfirstlane(src);
        dst = __builtin_amdgcn_readfirstlane(dst);

        int row = bwd[src];                          // fused feats[bwd] gather
        row = __builtin_amdgcn_readfirstlane(row);

        // Wave-uniform feats row -> scalar loads (s_load), 32 floats
        const float* f = feats + (long long)row * C_IN;
        float acc = 0.0f;
#pragma unroll
        for (int i = 0; i < C_IN; ++i) acc = fmaf(f[i], w[i], acc);

        // 64 lanes -> 256B contiguous atomic burst into the output row
        atomicAdd(out + (long long)dst * C_OUT + lane, acc);
    }
}

// ---------------------------------------------------------------------------
extern "C" void kernel_launch(void* const* d_in, const int* in_sizes, int n_in_cnt,
                              void* d_out, int out_size, void* d_ws, size_t ws_size,
                              hipStream_t stream) {
    const float* feats   = (const float*)d_in[0];
    const float* weight  = (const float*)d_in[1];
    const float* bias    = (const float*)d_in[2];
    const int*   bwd     = (const int*)d_in[3];
    const int*   in_idx  = (const int*)d_in[4];
    const int*   out_idx = (const int*)d_in[5];
    float*       out     = (float*)d_out;

    const int n_in   = in_sizes[0] / C_IN;   // 100000
    const int total4 = out_size / 4;         // N_out*64 / 4 float4s

    // 1) out = bias (also clears the 0xAA poison every call)
    hipLaunchKernelGGL(sic_init_bias, dim3(2048), dim3(256), 0, stream,
                       (float4*)out, (const float4*)bias, total4);

    // 2) gather-matvec-scatter over the rulebook
    dim3 grid(160, KK);   // 160*4 = 640 waves per kernel-offset k
    hipLaunchKernelGGL(sic_scatter, grid, dim3(256), 0, stream,
                       feats, weight, bwd, in_idx, out_idx, out, n_in);
}